// Round 1
// 70.641 us; speedup vs baseline: 1.0007x; 1.0007x over previous
//
#include <hip/hip_runtime.h>
#include <math.h>

// Problem constants (fixed by setup_inputs):
//   k_b=4, c_out=64, c_in=8, N=4096, m=8, ker=N/(2m)=256, c=2*pi*m/N
// Analytic collapse (journal R0) + new algebra (R1):
//   Kernel-B coefficient matrix is rank-deficient: Gi == Hr, Hi == -Gr exactly.
//   => per (b,o) the whole state is one complex S = Gr + i*Hr = -sum_i W_i * C_i,
//      W_i = |A|e^{i beta},  C_i = sum_t e^{i 2 pi m t / N} (zr_t + i zi_t).
//   Outputs are a rotation of S:  sr = -(c*Gr + s*Hr),  si = s*Gr - c*Hr,
//   so mag = sqrt(sr^2+si^2) = |S| is mu-INDEPENDENT -> gate computed once
//   per (b,o), not per element. Per-mu work: sin/cos + 4 FMA + 2 stores.
// Single fused kernel: each (b,o) block recomputes its own S from z (the
// 64 blocks sharing b re-read the same 256 KB slice -> L2-resident), then
// streams 32 KB of output. No workspace, no second launch, no dependency.
// All angles are exact multiples of 2*pi*(r/4096) -> HW v_sin/v_cos f32
// (REVOLUTION input) via builtins.

#define KB   4
#define COUT 64
#define CIN  8
#define NN   4096
#define INV_N   (1.0f / 4096.0f)
#define INV_2PI 0.15915494309189535f

__global__ __launch_bounds__(256) void fused_kernel(
    const float* __restrict__ zr,
    const float* __restrict__ zi,
    const float* __restrict__ A,
    const float* __restrict__ beta,
    const float* __restrict__ bias,
    const int* __restrict__ m_ptr,
    float* __restrict__ out)
{
    const int blk = blockIdx.x;            // b*COUT + o
    const int b   = blk >> 6;
    const int o   = blk & (COUT - 1);
    const int tid = threadIdx.x;           // 0..255
    const int m   = *m_ptr;

    // ---- Phase 1: per-thread partial complex Fourier sums C_i ----
    float cre[CIN], cim[CIN];
    #pragma unroll
    for (int i = 0; i < CIN; ++i) { cre[i] = 0.f; cim[i] = 0.f; }

    const float4* xr0 = (const float4*)(zr + b * CIN * NN);
    const float4* xi0 = (const float4*)(zi + b * CIN * NN);

    #pragma unroll
    for (int it = 0; it < NN / 1024; ++it) {       // 4 iterations
        const int vidx = it * 256 + tid;           // float4 index, coalesced
        const int t0   = vidx * 4;
        float sv[4], cv[4];
        #pragma unroll
        for (int j = 0; j < 4; ++j) {
            int r = (m * (t0 + j)) & (NN - 1);     // exact phase mod 1 rev
            float rev = (float)r * INV_N;
            sv[j] = __builtin_amdgcn_sinf(rev);
            cv[j] = __builtin_amdgcn_cosf(rev);
        }
        #pragma unroll
        for (int i = 0; i < CIN; ++i) {            // sin/cos reused across i
            float4 vr = xr0[i * (NN / 4) + vidx];
            float4 vi = xi0[i * (NN / 4) + vidx];
            #pragma unroll
            for (int j = 0; j < 4; ++j) {
                float a = (&vr.x)[j], bb = (&vi.x)[j];
                cre[i] += a * cv[j] - bb * sv[j];
                cim[i] += a * sv[j] + bb * cv[j];
            }
        }
    }

    // ---- fold W_i = |A| e^{i beta}:  S = -sum_i W_i * C_i ----
    float Sre = 0.f, Sim = 0.f;
    #pragma unroll
    for (int i = 0; i < CIN; ++i) {
        float a  = fabsf(A[o * CIN + i]);
        float rb = beta[o * CIN + i] * INV_2PI;    // radians -> revolutions
        float sb = __builtin_amdgcn_sinf(rb);
        float cb = __builtin_amdgcn_cosf(rb);
        float P = a * cb, Q = a * sb;
        Sre += -P * cre[i] + Q * cim[i];           // == per-i Gr contribution
        Sim += -Q * cre[i] - P * cim[i];           // == per-i Hr contribution
    }

    // ---- block reduction: wave(64) shuffle, then LDS across 4 waves ----
    #pragma unroll
    for (int off = 32; off > 0; off >>= 1) {
        Sre += __shfl_down(Sre, off);
        Sim += __shfl_down(Sim, off);
    }
    __shared__ float red[4][2];
    const int wave = tid >> 6, lane = tid & 63;
    if (lane == 0) { red[wave][0] = Sre; red[wave][1] = Sim; }
    __syncthreads();
    const float Gr = red[0][0] + red[1][0] + red[2][0] + red[3][0];
    const float Hr = red[0][1] + red[1][1] + red[2][1] + red[3][1];

    // ---- gate: mu-independent since |rotation(S)| = |S| ----
    const float mag  = sqrtf(Gr * Gr + Hr * Hr);
    const float x    = mag + bias[o];
    const float gate = 1.0f / ((1.0f + __expf(-x)) * (mag + 1e-5f));

    // ---- Phase 2: outputs (rotation of S, scaled by gate) ----
    const int base = blk << 12;                    // *4096
    const int half = KB * COUT * NN;               // offset of output 1
    #pragma unroll
    for (int k = 0; k < NN / 256; ++k) {
        int mu = tid + k * 256;
        int r = (m * mu) & (NN - 1);
        float rev = (float)r * INV_N;
        float smu = __builtin_amdgcn_sinf(rev);
        float cmu = __builtin_amdgcn_cosf(rev);
        float sr = -(cmu * Gr + smu * Hr);
        float si = smu * Gr - cmu * Hr;            // = -(cmu*Gi + smu*Hi)
        out[base + mu]        = gate * sr;
        out[half + base + mu] = gate * si;
    }
}

extern "C" void kernel_launch(void* const* d_in, const int* in_sizes, int n_in,
                              void* d_out, int out_size, void* d_ws, size_t ws_size,
                              hipStream_t stream) {
    const float* z_real = (const float*)d_in[0];
    const float* z_imag = (const float*)d_in[1];
    const float* A      = (const float*)d_in[2];
    const float* beta   = (const float*)d_in[3];
    const float* bias   = (const float*)d_in[4];
    const int*   m_ptr  = (const int*)d_in[5];
    float* out = (float*)d_out;

    fused_kernel<<<KB * COUT, 256, 0, stream>>>(z_real, z_imag, A, beta, bias,
                                                m_ptr, out);
}